// Round 2
// baseline (2164.959 us; speedup 1.0000x reference)
//
#include <hip/hip_runtime.h>
#include <hip/hip_bf16.h>
#include <stdint.h>

#define HD 512
#define BB 64
#define NSTEP 65          // 1 SOS + 64 teacher-forced tokens
#define MROW 4160         // BB * NSTEP valid output rows
#define MPAD 4224         // 33 * 128 padded rows for GEMM tiling
#define VSZ 32000
#define G3 1536
#define WSTRIDE 520       // padded LDS weight row stride (elements); 1040B = 16B-aligned

typedef float f32x4 __attribute__((ext_vector_type(4)));
typedef short bf16x8 __attribute__((ext_vector_type(8)));

__device__ __forceinline__ short f2b(float f) {
  union { float f; uint32_t u; } v; v.f = f;
  uint32_t r = v.u + 0x7FFFu + ((v.u >> 16) & 1u);
  return (short)(r >> 16);
}

__device__ __forceinline__ f32x4 mfma16(bf16x8 a, bf16x8 b, f32x4 c) {
  return __builtin_amdgcn_mfma_f32_16x16x32_bf16(a, b, c, 0, 0, 0);
}

__device__ __forceinline__ float sigm(float x) { return 1.f / (1.f + __expf(-x)); }

__device__ __forceinline__ void gl_lds16(const short* g, short* l) {
  __builtin_amdgcn_global_load_lds((const __attribute__((address_space(1))) void*)g,
                                   (__attribute__((address_space(3))) void*)l, 16, 0, 0);
}

// ---------------- zero scratch (rowsum + barrier) ----------------
__global__ void zero_kernel(float* rowsum, int* bar) {
  int i = blockIdx.x * 256 + threadIdx.x;
  if (i < MPAD) rowsum[i] = 0.f;
  if (i < 16) bar[i] = 0;
}

// ---------------- fp32 -> bf16 weight conversion ----------------
__global__ void convert_kernel(const float* __restrict__ Wfc, const float* __restrict__ Wi0,
                               short* dWfc, short* dWi0) {
  const int wfc4 = VSZ * HD / 4;
  const int tot4 = wfc4 + G3 * HD / 4;
  for (int i = blockIdx.x * 256 + threadIdx.x; i < tot4; i += gridDim.x * 256) {
    const float4* src; short4* dst; int j;
    if (i < wfc4) { src = (const float4*)Wfc; dst = (short4*)dWfc; j = i; }
    else          { src = (const float4*)Wi0; dst = (short4*)dWi0; j = i - wfc4; }
    float4 v = src[j];
    short4 s; s.x = f2b(v.x); s.y = f2b(v.y); s.z = f2b(v.z); s.w = f2b(v.w);
    dst[j] = s;
  }
}

// ---------------- embedding gather -> X bf16, row = t*64 + b ----------------
__global__ void gather_kernel(const float* __restrict__ emb, const int* __restrict__ tgt,
                              short* Xb) {
  const int tot4 = NSTEP * BB * HD / 4;   // 532480
  for (int i = blockIdx.x * 256 + threadIdx.x; i < tot4; i += gridDim.x * 256) {
    int row = i >> 7, q = i & 127;
    int t = row >> 6, b = row & 63;
    int tok = (t == 0) ? 1 : tgt[b * 65 + t - 1];
    float4 v = ((const float4*)(emb + (size_t)tok * HD))[q];
    short4 s; s.x = f2b(v.x); s.y = f2b(v.y); s.z = f2b(v.z); s.w = f2b(v.w);
    ((short4*)Xb)[i] = s;
  }
}

// ---------------- h0 = tanh(cv @ Winit^T + binit) into state buffer 1 ----------------
__global__ void __launch_bounds__(256) init_kernel(
    const float* __restrict__ cv, const float* __restrict__ Wi, const float* __restrict__ bi,
    float* hAf, float* hBf, short* hAb, short* hBb) {
  __shared__ float xr[HD];
  const int r = blockIdx.x;  // 0..127: l*64+b
  const int tid = threadIdx.x;
  for (int c = tid; c < HD; c += 256) xr[c] = cv[(size_t)r * HD + c];
  __syncthreads();
  const int b = r & 63;
  float* hf = (r < 64) ? hAf : hBf;
  short* hb = (r < 64) ? hAb : hBb;
  for (int c = tid; c < HD; c += 256) {
    const float4* w4 = (const float4*)(Wi + (size_t)c * HD);
    const float4* x4 = (const float4*)xr;
    float acc = bi[c];
    for (int k = 0; k < HD / 4; ++k) {
      float4 wv = w4[k], xv = x4[k];
      acc += wv.x * xv.x + wv.y * xv.y + wv.z * xv.z + wv.w * xv.w;
    }
    float v = tanhf(acc);
    hf[(size_t)BB * HD + (size_t)b * HD + c] = v;       // buffer 1 (state index -1)
    hb[(size_t)BB * HD + (size_t)b * HD + c] = f2b(v);
  }
}

// ---------------- generic bf16 GEMM: C[M x N] = A[M x 512] @ Bw[N x 512]^T + bias ----------------
// m97 recipe: 128x128 tile, BK=64, global_load_lds w=16, 16x16x32 MFMA.
// mvalid: rows >= mvalid are pad -> no store. do_expsum: atomicAdd per-row sum(exp(C)).
__global__ void __launch_bounds__(256) gemm_kernel(
    const short* __restrict__ A, const short* __restrict__ Bw,
    const float* __restrict__ bias, float* __restrict__ C,
    float* rowsum, int N, int mvalid, int do_expsum) {
  __shared__ short sA[128 * 64];
  __shared__ short sB[128 * 64];
  const int tid = threadIdx.x, lane = tid & 63, wv = tid >> 6;
  const size_t m0 = (size_t)blockIdx.y * 128;
  const size_t n0 = (size_t)blockIdx.x * 128;
  const int wm = (wv & 1) * 64, wn = (wv >> 1) * 64;
  f32x4 acc[4][4];
#pragma unroll
  for (int a = 0; a < 4; a++)
#pragma unroll
    for (int b = 0; b < 4; b++) acc[a][b] = (f32x4){0.f, 0.f, 0.f, 0.f};

  for (int k0 = 0; k0 < HD; k0 += 64) {
    __syncthreads();
#pragma unroll
    for (int c = 0; c < 4; ++c) {
      int cc = tid + c * 256;               // 0..1023 chunks of 16B
      int r = cc >> 3, co = (cc & 7) * 8;
      gl_lds16(A + (m0 + r) * HD + k0 + co, sA + cc * 8);
      gl_lds16(Bw + (n0 + r) * HD + k0 + co, sB + cc * 8);
    }
    __syncthreads();
#pragma unroll
    for (int kk = 0; kk < 2; ++kk) {
      const int ko = kk * 32 + (lane >> 4) * 8;
      bf16x8 af[4], bfr[4];
#pragma unroll
      for (int mt = 0; mt < 4; ++mt)
        af[mt] = *(const bf16x8*)(sA + (wm + mt * 16 + (lane & 15)) * 64 + ko);
#pragma unroll
      for (int nt = 0; nt < 4; ++nt)
        bfr[nt] = *(const bf16x8*)(sB + (wn + nt * 16 + (lane & 15)) * 64 + ko);
#pragma unroll
      for (int mt = 0; mt < 4; ++mt)
#pragma unroll
        for (int nt = 0; nt < 4; ++nt)
          acc[mt][nt] = mfma16(af[mt], bfr[nt], acc[mt][nt]);
    }
  }
  // epilogue: C layout col=lane&15, row=(lane>>4)*4+reg
  const int quad = lane >> 4, cl = lane & 15;
  float bv[4];
#pragma unroll
  for (int nt = 0; nt < 4; ++nt) bv[nt] = bias[n0 + wn + nt * 16 + cl];
#pragma unroll
  for (int mt = 0; mt < 4; ++mt) {
#pragma unroll
    for (int i = 0; i < 4; ++i) {
      size_t row = m0 + wm + mt * 16 + quad * 4 + i;
      if ((int)row >= mvalid) continue;      // uniform across the 16 lanes of this quad
      float es = 0.f;
#pragma unroll
      for (int nt = 0; nt < 4; ++nt) {
        float v = acc[mt][nt][i] + bv[nt];
        C[row * (size_t)N + n0 + wn + nt * 16 + cl] = v;
        if (do_expsum) es += __expf(v);
      }
      if (do_expsum) {
        es += __shfl_xor(es, 1, 64);
        es += __shfl_xor(es, 2, 64);
        es += __shfl_xor(es, 4, 64);
        es += __shfl_xor(es, 8, 64);
        if (cl == 0) atomicAdd(&rowsum[row], es);
      }
    }
  }
}

// ---------------- grid barrier: 2-level monotone counters ----------------
__device__ __forceinline__ void grid_barrier(int* bar, int gen) {
  __syncthreads();
  if (threadIdx.x == 0) {
    __threadfence();
    int leaf = blockIdx.x & 7;                 // 96 WGs -> 12 per leaf
    int lv = atomicAdd(&bar[leaf], 1);
    if ((lv % 12) == 11) {
      int rv = atomicAdd(&bar[8], 1);
      if ((rv % 8) == 7) {
        __threadfence();
        atomicAdd(&bar[9], 1);                 // release generation
      }
    }
    while (__hip_atomic_load(&bar[9], __ATOMIC_RELAXED, __HIP_MEMORY_SCOPE_AGENT) < gen) {
      __builtin_amdgcn_s_sleep(1);
    }
    __threadfence();
  }
  __syncthreads();
}

// ---------------- persistent GRU recurrence kernel ----------------
// 96 WGs x 256 thr. WG 0..31 = group1 (layer0 hidden GEMM + hA EW),
// WG 32..95 = group2 (layer1 input+hidden GEMMs + hB EW).
// Phase p: group1 computes hA_p (p<NSTEP); group2 computes hB_{p-1} (p>=1).
// One grid barrier per phase; NSTEP barriers total.
__global__ void __launch_bounds__(256) gru_kernel(
    const float* __restrict__ gi0, const float* __restrict__ Wh0,
    const float* __restrict__ Wi1, const float* __restrict__ Wh1,
    const float* __restrict__ bh0, const float* __restrict__ bi1, const float* __restrict__ bh1,
    float* hAf, float* hBf, short* hAb, short* hBb, short* ysb, int* bar) {
  extern __shared__ char smem[];
  short* wlds = (short*)smem;                       // 96 x WSTRIDE bf16
  float* exch = (float*)(smem + 96 * WSTRIDE * 2);  // [2 src][3 gate][32 row][16 col]

  const int tid = threadIdx.x;
  const int lane = tid & 63;
  const int wv = tid >> 6;
  const int wg = blockIdx.x;
  const bool g2 = (wg >= 32);
  int bh, slice;
  if (!g2) { bh = wg >> 4; slice = wg & 15; }           // 32-col hidden slice
  else { int w = wg - 32; bh = w >> 5; slice = w & 31; } // 16-col hidden slice

  // --- load bf16 weights into LDS (persistent across all phases) ---
  if (!g2) {
    const int j0 = slice * 32;
    for (int e = tid; e < 96 * 128; e += 256) {
      int R = e >> 7, q = e & 127;
      int g = R >> 5, jl = R & 31;
      float4 v = ((const float4*)(Wh0 + ((size_t)(g * HD + j0 + jl)) * HD))[q];
      short4 s; s.x = f2b(v.x); s.y = f2b(v.y); s.z = f2b(v.z); s.w = f2b(v.w);
      *(short4*)(wlds + R * WSTRIDE + q * 4) = s;
    }
  } else {
    const int j0 = slice * 16;
    for (int e = tid; e < 96 * 128; e += 256) {
      int R = e >> 7, q = e & 127;
      int src = R / 48, rr = R - src * 48;
      int g = rr >> 4, jl = rr & 15;
      const float* W = src ? Wh1 : Wi1;
      float4 v = ((const float4*)(W + ((size_t)(g * HD + j0 + jl)) * HD))[q];
      short4 s; s.x = f2b(v.x); s.y = f2b(v.y); s.z = f2b(v.z); s.w = f2b(v.w);
      *(short4*)(wlds + R * WSTRIDE + q * 4) = s;
    }
  }
  __syncthreads();

  const int m = wv & 1;       // M-tile (16 rows) within 32-row batch-half
  const int sub = wv >> 1;    // group1: 16-col half; group2: src (0=gi1,1=gh1)
  const int quad = lane >> 4;
  const int kq = quad * 8;
  const int arow = bh * 32 + m * 16 + (lane & 15);
  const int l15 = lane & 15;

  for (int p = 0; p <= NSTEP; ++p) {
    const int rbuf = (p + 1) & 1;   // buffer holding state index p-1
    const int wbuf = p & 1;
    if (!g2) {
      if (p < NSTEP) {
        // gh0_p = hA_{p-1} @ Wh0^T (its 96 gate cols), then EW -> hA_p
        const short* Ab = hAb + (size_t)rbuf * BB * HD + (size_t)arow * HD;
        const short* B0 = wlds + (0 * 32 + sub * 16 + l15) * WSTRIDE;
        const short* B1 = wlds + (1 * 32 + sub * 16 + l15) * WSTRIDE;
        const short* B2 = wlds + (2 * 32 + sub * 16 + l15) * WSTRIDE;
        f32x4 a0 = {0.f,0.f,0.f,0.f}, a1 = {0.f,0.f,0.f,0.f}, a2 = {0.f,0.f,0.f,0.f};
#pragma unroll
        for (int ki = 0; ki < 16; ++ki) {
          const int ko = ki * 32 + kq;
          bf16x8 a = *(const bf16x8*)(Ab + ko);
          a0 = mfma16(a, *(const bf16x8*)(B0 + ko), a0);
          a1 = mfma16(a, *(const bf16x8*)(B1 + ko), a1);
          a2 = mfma16(a, *(const bf16x8*)(B2 + ko), a2);
        }
        const int jg = slice * 32 + sub * 16 + l15;
        const float br = bh0[jg], bz = bh0[HD + jg], bn = bh0[2 * HD + jg];
#pragma unroll
        for (int i = 0; i < 4; ++i) {
          int b_ = bh * 32 + m * 16 + quad * 4 + i;
          const float* gi = gi0 + ((size_t)p * BB + b_) * G3;
          float r = sigm(gi[jg] + a0[i] + br);
          float z = sigm(gi[HD + jg] + a1[i] + bz);
          float n = tanhf(gi[2 * HD + jg] + r * (a2[i] + bn));
          float hp = hAf[(size_t)rbuf * BB * HD + (size_t)b_ * HD + jg];
          float hv = (1.f - z) * n + z * hp;
          hAf[(size_t)wbuf * BB * HD + (size_t)b_ * HD + jg] = hv;
          hAb[(size_t)wbuf * BB * HD + (size_t)b_ * HD + jg] = f2b(hv);
        }
      }
    } else {
      if (p >= 1) {
        // gi1_{p-1} = hA_{p-1} @ Wi1^T ; gh1_{p-1} = hB_{p-2} @ Wh1^T ; EW -> hB_{p-1}
        const short* Ab = sub ? (hBb + (size_t)wbuf * BB * HD + (size_t)arow * HD)
                              : (hAb + (size_t)rbuf * BB * HD + (size_t)arow * HD);
        const short* B0 = wlds + (sub * 48 + 0 + l15) * WSTRIDE;
        const short* B1 = wlds + (sub * 48 + 16 + l15) * WSTRIDE;
        const short* B2 = wlds + (sub * 48 + 32 + l15) * WSTRIDE;
        f32x4 a0 = {0.f,0.f,0.f,0.f}, a1 = {0.f,0.f,0.f,0.f}, a2 = {0.f,0.f,0.f,0.f};
#pragma unroll
        for (int ki = 0; ki < 16; ++ki) {
          const int ko = ki * 32 + kq;
          bf16x8 a = *(const bf16x8*)(Ab + ko);
          a0 = mfma16(a, *(const bf16x8*)(B0 + ko), a0);
          a1 = mfma16(a, *(const bf16x8*)(B1 + ko), a1);
          a2 = mfma16(a, *(const bf16x8*)(B2 + ko), a2);
        }
#pragma unroll
        for (int i = 0; i < 4; ++i) {
          int rloc = m * 16 + quad * 4 + i;
          exch[((sub * 3 + 0) * 32 + rloc) * 16 + l15] = a0[i];
          exch[((sub * 3 + 1) * 32 + rloc) * 16 + l15] = a1[i];
          exch[((sub * 3 + 2) * 32 + rloc) * 16 + l15] = a2[i];
        }
        __syncthreads();
        const int t = p - 1;
        for (int e = tid; e < 512; e += 256) {
          int rloc = e >> 4, c = e & 15;
          int b_ = bh * 32 + rloc;
          int jg = slice * 16 + c;
          float ir = exch[(0 * 32 + rloc) * 16 + c];
          float iz = exch[(1 * 32 + rloc) * 16 + c];
          float in_ = exch[(2 * 32 + rloc) * 16 + c];
          float hr = exch[(3 * 32 + rloc) * 16 + c];
          float hz = exch[(4 * 32 + rloc) * 16 + c];
          float hn = exch[(5 * 32 + rloc) * 16 + c];
          float r = sigm(ir + bi1[jg] + hr + bh1[jg]);
          float z = sigm(iz + bi1[HD + jg] + hz + bh1[HD + jg]);
          float n = tanhf(in_ + bi1[2 * HD + jg] + r * (hn + bh1[2 * HD + jg]));
          float hp = hBf[(size_t)wbuf * BB * HD + (size_t)b_ * HD + jg];
          float hv = (1.f - z) * n + z * hp;
          hBf[(size_t)rbuf * BB * HD + (size_t)b_ * HD + jg] = hv;
          short h16 = f2b(hv);
          hBb[(size_t)rbuf * BB * HD + (size_t)b_ * HD + jg] = h16;
          ysb[((size_t)b_ * NSTEP + t) * HD + jg] = h16;   // output row = b*65 + t
        }
      }
    }
    if (p < NSTEP) grid_barrier(bar, p + 1);
  }
}

// ---------------- pass 2: out = logits - log(rowsum) in place ----------------
__global__ void logsm_kernel(float* __restrict__ out, const float* __restrict__ rowsum) {
  const unsigned tot4 = (unsigned)MROW * (VSZ / 4);    // 33,280,000
  for (unsigned i = blockIdx.x * 256 + threadIdx.x; i < tot4; i += gridDim.x * 256) {
    unsigned row = i / (VSZ / 4);
    float ls = __logf(rowsum[row]);
    float4 v = ((const float4*)out)[i];
    v.x -= ls; v.y -= ls; v.z -= ls; v.w -= ls;
    ((float4*)out)[i] = v;
  }
}

extern "C" void kernel_launch(void* const* d_in, const int* in_sizes, int n_in,
                              void* d_out, int out_size, void* d_ws, size_t ws_size,
                              hipStream_t stream) {
  (void)in_sizes; (void)n_in; (void)out_size; (void)ws_size;
  const float* cv    = (const float*)d_in[0];
  const int*   tgt   = (const int*)d_in[1];
  const float* emb   = (const float*)d_in[2];
  const float* Winit = (const float*)d_in[3];
  const float* binit = (const float*)d_in[4];
  const float* Wi0   = (const float*)d_in[5];
  const float* Wh0   = (const float*)d_in[6];
  const float* bi0   = (const float*)d_in[7];
  const float* bh0   = (const float*)d_in[8];
  const float* Wi1   = (const float*)d_in[9];
  const float* Wh1   = (const float*)d_in[10];
  const float* bi1   = (const float*)d_in[11];
  const float* bh1   = (const float*)d_in[12];
  const float* Wfc   = (const float*)d_in[13];
  const float* bfc   = (const float*)d_in[14];
  float* out = (float*)d_out;

  char* ws = (char*)d_ws;
  size_t off = 0;
  short* dWfc = (short*)(ws + off); off += (size_t)VSZ * HD * 2;        // 32.77 MB
  short* dWi0 = (short*)(ws + off); off += (size_t)G3 * HD * 2;         // 1.57 MB
  short* Xb   = (short*)(ws + off); off += (size_t)MPAD * HD * 2;       // 4.33 MB
  float* gi0  = (float*)(ws + off); off += (size_t)MPAD * G3 * 4;       // 25.95 MB
  short* ysb  = (short*)(ws + off); off += (size_t)MPAD * HD * 2;       // 4.33 MB
  float* hAf  = (float*)(ws + off); off += (size_t)2 * BB * HD * 4;
  float* hBf  = (float*)(ws + off); off += (size_t)2 * BB * HD * 4;
  short* hAb  = (short*)(ws + off); off += (size_t)2 * BB * HD * 2;
  short* hBb  = (short*)(ws + off); off += (size_t)2 * BB * HD * 2;
  float* rowsum = (float*)(ws + off); off += (size_t)MPAD * 4;
  int*   bar  = (int*)(ws + off); off += 256;

  zero_kernel<<<17, 256, 0, stream>>>(rowsum, bar);
  convert_kernel<<<2048, 256, 0, stream>>>(Wfc, Wi0, dWfc, dWi0);
  gather_kernel<<<1024, 256, 0, stream>>>(emb, tgt, Xb);
  init_kernel<<<128, 256, 0, stream>>>(cv, Winit, binit, hAf, hBf, hAb, hBb);
  // gi0 = X @ Wi0^T + bi0  (4160 valid rows padded to 4224, N=1536, K=512)
  gemm_kernel<<<dim3(G3 / 128, MPAD / 128), 256, 0, stream>>>(
      Xb, dWi0, bi0, gi0, nullptr, G3, MPAD, 0);

  const size_t smem = (size_t)96 * WSTRIDE * 2 + 6 * 32 * 16 * 4;  // 112128 B
  hipFuncSetAttribute((const void*)gru_kernel,
                      hipFuncAttributeMaxDynamicSharedMemorySize, (int)smem);
  gru_kernel<<<96, 256, smem, stream>>>(gi0, Wh0, Wi1, Wh1, bh0, bi1, bh1,
                                        hAf, hBf, hAb, hBb, ysb, bar);

  // logits = ys @ Wfc^T + bfc into d_out (4160 valid rows), fused exp-rowsum
  gemm_kernel<<<dim3(VSZ / 128, MPAD / 128), 256, 0, stream>>>(
      ysb, dWfc, bfc, out, rowsum, VSZ, MROW, 1);
  logsm_kernel<<<8192, 256, 0, stream>>>(out, rowsum);
}